// Round 4
// baseline (315.047 us; speedup 1.0000x reference)
//
#include <hip/hip_runtime.h>
#include <hip/hip_bf16.h>

#define MD 8192
#define KD 4096
#define ND 4096

typedef __bf16 bf16x8 __attribute__((ext_vector_type(8)));
typedef float f32x4 __attribute__((ext_vector_type(4)));

__device__ __forceinline__ float gelu_ss(float v) {
    float t = 0.7978845608f * fmaf(0.044715f * v * v, v, v);
    float r = t * __builtin_amdgcn_rcpf(1.0f + fabsf(t));
    return 0.5f * v * (1.0f + r);
}

// ---------------------------------------------------------------------------
// fp32 -> bf16 convert (memory-bound; inputs are L3-resident after 1st replay)
// ---------------------------------------------------------------------------
__global__ void cvt_bf16(const float* __restrict__ in, __bf16* __restrict__ out, int n8) {
    int i = blockIdx.x * 256 + threadIdx.x;
    int stride = gridDim.x * 256;
    for (; i < n8; i += stride) {
        const float4* p = (const float4*)(in + (size_t)i * 8);
        float4 a = p[0], b = p[1];
        bf16x8 v;
        v[0]=(__bf16)a.x; v[1]=(__bf16)a.y; v[2]=(__bf16)a.z; v[3]=(__bf16)a.w;
        v[4]=(__bf16)b.x; v[5]=(__bf16)b.y; v[6]=(__bf16)b.z; v[7]=(__bf16)b.w;
        *(bf16x8*)(out + (size_t)i * 8) = v;
    }
}

// ---------------------------------------------------------------------------
// GEMM+epilogue: 256x256, BK=32, quad-buffered LDS, global_load_lds lead-3,
// counted vmcnt (T4), 2-phase-per-tile interleave (T3), setprio (T5).
// ---------------------------------------------------------------------------
#define BMg 256
#define BNg 256
#define BKg 32
#define KT  (KD / BKg)   // 128

__device__ __forceinline__ void gload_lds16(const void* g, void* l) {
    __builtin_amdgcn_global_load_lds(
        (const __attribute__((address_space(1))) void*)g,
        (__attribute__((address_space(3))) void*)l, 16, 0, 0);
}

__global__ __launch_bounds__(512, 2) void gemm_bf16_lse(
    const __bf16* __restrict__ xb, const __bf16* __restrict__ Wb,
    const float* __restrict__ bias, float* __restrict__ rowsum)
{
    // 4 bufs x (A,B) x 256x32 bf16 = 128 KiB
    __shared__ alignas(16) __bf16 lds[4][2][BMg * BKg];

    const unsigned nblk = (MD / BMg) * (ND / BNg);   // 512
    unsigned bid  = blockIdx.x;
    unsigned sbid = (bid & 7u) * (nblk / 8u) + (bid >> 3);
    unsigned bm = sbid / (ND / BNg);
    unsigned bn = sbid % (ND / BNg);

    const unsigned tid  = threadIdx.x;
    const unsigned lane = tid & 63u;
    const unsigned wid  = tid >> 6;      // 0..7
    const unsigned wr   = wid >> 2;      // 0..1 -> 128 rows
    const unsigned wc   = wid & 3u;      // 0..3 -> 64 cols
    const unsigned lr   = lane & 15u;
    const unsigned kg   = lane >> 4;

    // staging source addresses (per-lane, pre-swizzled: c ^= (row>>1)&3)
    unsigned s0 = tid, s1 = tid + 512u;
    unsigned r0 = s0 >> 2, c0 = s0 & 3u;
    unsigned r1 = s1 >> 2, c1 = s1 & 3u;
    unsigned cg0 = c0 ^ ((r0 >> 1) & 3u);
    unsigned cg1 = c1 ^ ((r1 >> 1) & 3u);
    const __bf16* ga0 = xb + (size_t)(bm * BMg + r0) * KD + cg0 * 8u;
    const __bf16* ga1 = xb + (size_t)(bm * BMg + r1) * KD + cg1 * 8u;
    const __bf16* gb0 = Wb + (size_t)(bn * BNg + r0) * KD + cg0 * 8u;
    const __bf16* gb1 = Wb + (size_t)(bn * BNg + r1) * KD + cg1 * 8u;

    f32x4 acc[8][4] = {};
    bf16x8 afr0[4], afr1[4], bfr[4];

    auto stageA = [&](unsigned bsel) {
        gload_lds16(ga0, &lds[bsel][0][(wid * 64u + 0u * 512u) * 8u]);
        gload_lds16(ga1, &lds[bsel][0][(wid * 64u + 1u * 512u) * 8u]);
        ga0 += BKg; ga1 += BKg;
    };
    auto stageB = [&](unsigned bsel) {
        gload_lds16(gb0, &lds[bsel][1][(wid * 64u + 0u * 512u) * 8u]);
        gload_lds16(gb1, &lds[bsel][1][(wid * 64u + 1u * 512u) * 8u]);
        gb0 += BKg; gb1 += BKg;
    };
    auto loadB = [&](unsigned bsel) {
        const char* BsB = (const char*)&lds[bsel][1][0];
        #pragma unroll
        for (int nf = 0; nf < 4; ++nf) {
            unsigned row = wc * 64u + nf * 16u + lr;
            bfr[nf] = *(const bf16x8*)(BsB + row * 64u + (kg ^ ((row >> 1) & 3u)) * 16u);
        }
    };
    auto loadA = [&](unsigned bsel, unsigned mh, bf16x8* afr) {
        const char* AsB = (const char*)&lds[bsel][0][0];
        #pragma unroll
        for (int a = 0; a < 4; ++a) {
            unsigned row = wr * 128u + (mh * 4u + a) * 16u + lr;
            afr[a] = *(const bf16x8*)(AsB + row * 64u + (kg ^ ((row >> 1) & 3u)) * 16u);
        }
    };
    auto mfmaHalf = [&](unsigned mh, bf16x8* afr) {
        __builtin_amdgcn_s_setprio(1);
        #pragma unroll
        for (int a = 0; a < 4; ++a)
            #pragma unroll
            for (int nf = 0; nf < 4; ++nf)
                acc[mh * 4 + a][nf] = __builtin_amdgcn_mfma_f32_16x16x32_bf16(
                    afr[a], bfr[nf], acc[mh * 4 + a][nf], 0, 0, 0);
        __builtin_amdgcn_s_setprio(0);
    };

    // prologue: prefetch tiles 0,1,2 (12 loads/thread in flight)
    stageA(0); stageB(0); stageA(1); stageB(1); stageA(2); stageB(2);

    for (int t = 0; t < KT; ++t) {
        unsigned cb = (unsigned)t & 3u;
        // ---- B0: tile t landed for ALL waves; prev-iter reads drained ----
        if (t < KT - 2)      asm volatile("s_waitcnt vmcnt(8)" ::: "memory");
        else if (t == KT - 2) asm volatile("s_waitcnt vmcnt(4)" ::: "memory");
        else                  asm volatile("s_waitcnt vmcnt(0)" ::: "memory");
        __builtin_amdgcn_s_barrier();
        __builtin_amdgcn_sched_barrier(0);
        // ---- phase 0: reads + stage-A(t+3) || MFMA m-half 0 ----
        loadB(cb);
        loadA(cb, 0, afr0);
        if (t < KT - 3) stageA((unsigned)(t + 3) & 3u);
        __builtin_amdgcn_s_barrier();
        asm volatile("s_waitcnt lgkmcnt(0)" ::: "memory");
        __builtin_amdgcn_sched_barrier(0);
        mfmaHalf(0, afr0);
        __builtin_amdgcn_s_barrier();
        // ---- phase 1: reads + stage-B(t+3) || MFMA m-half 1 ----
        loadA(cb, 1, afr1);
        if (t < KT - 3) stageB((unsigned)(t + 3) & 3u);
        __builtin_amdgcn_s_barrier();
        asm volatile("s_waitcnt lgkmcnt(0)" ::: "memory");
        __builtin_amdgcn_sched_barrier(0);
        mfmaHalf(1, afr1);
    }

    // ---- epilogue: bias + leaky^2 + gelu^2 + exp + row partial sums ----
    // C/D layout: col = lane&15 (=lr), row = kg*4 + j
    unsigned row_base = bm * BMg + wr * 128u;
    unsigned col_base = bn * BNg + wc * 64u;
    float bb[4];
    #pragma unroll
    for (int nf = 0; nf < 4; ++nf) bb[nf] = bias[col_base + nf * 16u + lr];
    #pragma unroll
    for (int mf = 0; mf < 8; ++mf) {
        float s[4] = {0.f, 0.f, 0.f, 0.f};
        #pragma unroll
        for (int nf = 0; nf < 4; ++nf) {
            #pragma unroll
            for (int j = 0; j < 4; ++j) {
                float v = acc[mf][nf][j] + bb[nf];
                v = v > 0.0f ? v : 1e-4f * v;      // two leaky-relus fused
                v = gelu_ss(gelu_ss(v));
                s[j] += __expf(v);
            }
        }
        #pragma unroll
        for (int j = 0; j < 4; ++j) {
            float t = s[j];
            t += __shfl_xor(t, 1);
            t += __shfl_xor(t, 2);
            t += __shfl_xor(t, 4);
            t += __shfl_xor(t, 8);
            if (lr == 0)
                atomicAdd(&rowsum[row_base + mf * 16u + kg * 4u + j], t);
        }
    }
}

// ---------------------------------------------------------------------------
// Fallback (round-2 kernel): fused fp32 staging, used only if ws too small.
// ---------------------------------------------------------------------------
#define BM 256
#define BN 256
#define BK 64
#define NBLK ((MD / BM) * (ND / BN))

__device__ __forceinline__ unsigned swz(unsigned row, unsigned kbyte) {
    return row * (BK * 2u) + (kbyte ^ ((row & 7u) << 4));
}

__global__ __launch_bounds__(512, 1) void fused_gemm_lse(
    const float* __restrict__ x, const float* __restrict__ W,
    const float* __restrict__ bias, float* __restrict__ rowsum)
{
    __shared__ alignas(16) __bf16 lds[2][2][BM * BK];
    unsigned bid  = blockIdx.x;
    unsigned sbid = (bid & 7u) * (NBLK / 8u) + (bid >> 3);
    unsigned bm = sbid / (ND / BN);
    unsigned bn = sbid % (ND / BN);
    const unsigned tid  = threadIdx.x;
    const unsigned lane = tid & 63u;
    const unsigned wid  = tid >> 6;
    const unsigned wr   = wid >> 2;
    const unsigned wc   = wid & 3u;
    const unsigned lr   = lane & 15u;
    const unsigned kg   = lane >> 4;
    const float* gA = x + (size_t)bm * BM * KD;
    const float* gB = W + (size_t)bn * BN * KD;
    const unsigned s_row = tid >> 3;
    const unsigned s_c8  = tid & 7u;
    f32x4 acc[8][4] = {};
    float4 ra[8], rb[8];
    auto issue = [&](const float* g, int kt, float4* r) {
        #pragma unroll
        for (int i = 0; i < 4; ++i) {
            unsigned row = s_row + 64u * i;
            size_t goff = (size_t)row * KD + (size_t)kt * BK + (size_t)s_c8 * 8u;
            r[i * 2]     = *(const float4*)(g + goff);
            r[i * 2 + 1] = *(const float4*)(g + goff + 4);
        }
    };
    auto writeT = [&](char* dst, const float4* r) {
        #pragma unroll
        for (int i = 0; i < 4; ++i) {
            unsigned row = s_row + 64u * i;
            float4 lo = r[i * 2], hi = r[i * 2 + 1];
            bf16x8 v;
            v[0]=(__bf16)lo.x; v[1]=(__bf16)lo.y; v[2]=(__bf16)lo.z; v[3]=(__bf16)lo.w;
            v[4]=(__bf16)hi.x; v[5]=(__bf16)hi.y; v[6]=(__bf16)hi.z; v[7]=(__bf16)hi.w;
            *(bf16x8*)(dst + swz(row, s_c8 * 16u)) = v;
        }
    };
    auto compute = [&](int cur) {
        const char* AsB = (const char*)&lds[cur][0][0];
        const char* BsB = (const char*)&lds[cur][1][0];
        #pragma unroll
        for (int ks = 0; ks < 2; ++ks) {
            unsigned kb = (unsigned)ks * 64u + kg * 16u;
            bf16x8 bfr[4];
            #pragma unroll
            for (int ni = 0; ni < 4; ++ni)
                bfr[ni] = *(const bf16x8*)(BsB + swz(wc * 64u + ni * 16u + lr, kb));
            #pragma unroll
            for (int mh = 0; mh < 2; ++mh) {
                bf16x8 af[4];
                #pragma unroll
                for (int a = 0; a < 4; ++a)
                    af[a] = *(const bf16x8*)(AsB + swz(wr * 128u + mh * 64u + a * 16u + lr, kb));
                __builtin_amdgcn_s_setprio(1);
                #pragma unroll
                for (int a = 0; a < 4; ++a)
                    #pragma unroll
                    for (int ni = 0; ni < 4; ++ni)
                        acc[mh * 4 + a][ni] = __builtin_amdgcn_mfma_f32_16x16x32_bf16(
                            af[a], bfr[ni], acc[mh * 4 + a][ni], 0, 0, 0);
                __builtin_amdgcn_s_setprio(0);
            }
        }
    };
    issue(gA, 0, ra); issue(gB, 0, rb);
    writeT((char*)&lds[0][0][0], ra);
    writeT((char*)&lds[0][1][0], rb);
    __syncthreads();
    int cur = 0;
    for (int kt = 0; kt < KD / BK - 1; ++kt) {
        issue(gA, kt + 1, ra);
        issue(gB, kt + 1, rb);
        compute(cur);
        writeT((char*)&lds[cur ^ 1][0][0], ra);
        writeT((char*)&lds[cur ^ 1][1][0], rb);
        __syncthreads();
        cur ^= 1;
    }
    compute(cur);
    unsigned row_base = bm * BM + wr * 128u;
    unsigned col_base = bn * BN + wc * 64u;
    float bb[4];
    #pragma unroll
    for (int ni = 0; ni < 4; ++ni) bb[ni] = bias[col_base + ni * 16u + lr];
    #pragma unroll
    for (int mi = 0; mi < 8; ++mi) {
        float s[4] = {0.f, 0.f, 0.f, 0.f};
        #pragma unroll
        for (int ni = 0; ni < 4; ++ni) {
            #pragma unroll
            for (int j = 0; j < 4; ++j) {
                float v = acc[mi][ni][j] + bb[ni];
                v = v > 0.0f ? v : 1e-4f * v;
                v = gelu_ss(gelu_ss(v));
                s[j] += __expf(v);
            }
        }
        #pragma unroll
        for (int j = 0; j < 4; ++j) {
            float t = s[j];
            t += __shfl_xor(t, 1);
            t += __shfl_xor(t, 2);
            t += __shfl_xor(t, 4);
            t += __shfl_xor(t, 8);
            if (lr == 0)
                atomicAdd(&rowsum[row_base + mi * 16u + kg * 4u + j], t);
        }
    }
}

__global__ void lse_log(float* __restrict__ out) {
    int i = blockIdx.x * 256 + threadIdx.x;
    if (i < MD) out[i] = logf(out[i]);
}

extern "C" void kernel_launch(void* const* d_in, const int* in_sizes, int n_in,
                              void* d_out, int out_size, void* d_ws, size_t ws_size,
                              hipStream_t stream) {
    (void)in_sizes; (void)n_in; (void)out_size;
    const float* x = (const float*)d_in[0];
    const float* W = (const float*)d_in[1];
    const float* b = (const float*)d_in[2];
    float* out = (float*)d_out;

    hipMemsetAsync(out, 0, (size_t)MD * sizeof(float), stream);

    size_t need = ((size_t)MD * KD + (size_t)ND * KD) * sizeof(__bf16);  // 100.7 MB
    if (ws_size >= need) {
        __bf16* xb = (__bf16*)d_ws;
        __bf16* Wb = xb + (size_t)MD * KD;
        cvt_bf16<<<2048, 256, 0, stream>>>(x, xb, MD * KD / 8);
        cvt_bf16<<<2048, 256, 0, stream>>>(W, Wb, ND * KD / 8);
        gemm_bf16_lse<<<(MD / BMg) * (ND / BNg), 512, 0, stream>>>(xb, Wb, b, out);
    } else {
        fused_gemm_lse<<<NBLK, 512, 0, stream>>>(x, W, b, out);
    }
    lse_log<<<MD / 256, 256, 0, stream>>>(out);
}

// Round 5
// 291.439 us; speedup vs baseline: 1.0810x; 1.0810x over previous
//
#include <hip/hip_runtime.h>
#include <hip/hip_bf16.h>

#define MD 8192
#define KD 4096
#define ND 4096

typedef __bf16 bf16x8 __attribute__((ext_vector_type(8)));
typedef float f32x4 __attribute__((ext_vector_type(4)));

__device__ __forceinline__ float gelu_ss(float v) {
    float t = 0.7978845608f * fmaf(0.044715f * v * v, v, v);
    float r = t * __builtin_amdgcn_rcpf(1.0f + fabsf(t));
    return 0.5f * v * (1.0f + r);
}

// ---------------------------------------------------------------------------
// fp32 -> bf16 convert (memory-bound; inputs are L3-resident after 1st replay)
// ---------------------------------------------------------------------------
__global__ void cvt_bf16(const float* __restrict__ in, __bf16* __restrict__ out, int n8) {
    int i = blockIdx.x * 256 + threadIdx.x;
    int stride = gridDim.x * 256;
    for (; i < n8; i += stride) {
        const float4* p = (const float4*)(in + (size_t)i * 8);
        float4 a = p[0], b = p[1];
        bf16x8 v;
        v[0]=(__bf16)a.x; v[1]=(__bf16)a.y; v[2]=(__bf16)a.z; v[3]=(__bf16)a.w;
        v[4]=(__bf16)b.x; v[5]=(__bf16)b.y; v[6]=(__bf16)b.z; v[7]=(__bf16)b.w;
        *(bf16x8*)(out + (size_t)i * 8) = v;
    }
}

// ---------------------------------------------------------------------------
// GEMM+epilogue: 256x256, BK=64, 2 LDS bufs, m201-style 4-phase cadence.
// Phase q: {ds_reads, 1 stage-unit, barrier, lgkm(0), 16 MFMA}.
// vmcnt(4) once per K-tile (B staged 2 tiles ahead into dead B-region).
// ---------------------------------------------------------------------------
#define BMg 256
#define BNg 256
#define BKg 64
#define KTg (KD / BKg)   // 64

__device__ __forceinline__ void gload_lds16(const void* g, void* l) {
    __builtin_amdgcn_global_load_lds(
        (const __attribute__((address_space(1))) void*)g,
        (__attribute__((address_space(3))) void*)l, 16, 0, 0);
}

__global__ __launch_bounds__(512, 1) void gemm_bf16_lse(
    const __bf16* __restrict__ xb, const __bf16* __restrict__ Wb,
    const float* __restrict__ bias, float* __restrict__ rowsum)
{
    // [buf][A=0/B=1][256*64 bf16] = 2 x 2 x 32 KiB = 128 KiB
    __shared__ alignas(16) __bf16 lds[2][2][BMg * BKg];

    const unsigned nblk = (MD / BMg) * (ND / BNg);   // 512
    unsigned bid  = blockIdx.x;
    unsigned sbid = (bid & 7u) * (nblk / 8u) + (bid >> 3);
    unsigned bm = sbid / (ND / BNg);
    unsigned bn = sbid % (ND / BNg);

    const unsigned tid  = threadIdx.x;
    const unsigned lane = tid & 63u;
    const unsigned wid  = tid >> 6;      // 0..7
    const unsigned wr   = wid >> 2;      // 0..1 -> 128 rows
    const unsigned wc   = wid & 3u;      // 0..3 -> 64 cols
    const unsigned lr   = lane & 15u;
    const unsigned kg   = lane >> 4;
    const unsigned x7   = lr & 7u;       // row-derived swizzle bits

    // --- staging geometry: unit = 128 rows x 64 cols (16 KiB), 2 gloads/thread.
    // chunk ch in [0,1024): row = ch>>3, slot s = ch&7; LDS linear (DMA),
    // global col-slot pre-swizzled cg = s ^ (row&7)  (rule #21).
    unsigned ch0 = tid, ch1 = tid + 512u;
    unsigned sr0 = ch0 >> 3, cg0 = (ch0 & 7u) ^ (sr0 & 7u);
    unsigned sr1 = ch1 >> 3, cg1 = (ch1 & 7u) ^ (sr1 & 7u);
    const __bf16* gA0 = xb + (size_t)(bm * BMg + sr0) * KD + cg0 * 8u;
    const __bf16* gA1 = xb + (size_t)(bm * BMg + sr1) * KD + cg1 * 8u;
    const __bf16* gB0 = Wb + (size_t)(bn * BNg + sr0) * KD + cg0 * 8u;
    const __bf16* gB1 = Wb + (size_t)(bn * BNg + sr1) * KD + cg1 * 8u;

    f32x4 acc[8][4] = {};
    bf16x8 bfr[4][2];   // B fragments [nf][ks], live across the 4 phases

    auto stA = [&](unsigned bsel, unsigned half, int t) {
        size_t off = (size_t)half * 128u * KD + (size_t)t * 64u;
        gload_lds16(gA0 + off, &lds[bsel][0][(half * 1024u + ch0) * 8u]);
        gload_lds16(gA1 + off, &lds[bsel][0][(half * 1024u + ch1) * 8u]);
    };
    auto stB = [&](unsigned bsel, unsigned half, int t) {
        size_t off = (size_t)half * 128u * KD + (size_t)t * 64u;
        gload_lds16(gB0 + off, &lds[bsel][1][(half * 1024u + ch0) * 8u]);
        gload_lds16(gB1 + off, &lds[bsel][1][(half * 1024u + ch1) * 8u]);
    };
    // fragment ds_reads; row stride 128B, slot c = ks*4+kg swizzled by row&7
    auto loadB = [&](unsigned bsel) {
        const char* Bs = (const char*)&lds[bsel][1][0];
        #pragma unroll
        for (int nf = 0; nf < 4; ++nf) {
            unsigned ro = (wc * 64u + nf * 16u + lr) * 128u;
            bfr[nf][0] = *(const bf16x8*)(Bs + ro + ((kg     ) ^ x7) * 16u);
            bfr[nf][1] = *(const bf16x8*)(Bs + ro + ((kg + 4u) ^ x7) * 16u);
        }
    };
    auto loadA = [&](unsigned bsel, unsigned q, bf16x8 (*afr)[2]) {
        const char* As = (const char*)&lds[bsel][0][0];
        #pragma unroll
        for (int a = 0; a < 2; ++a) {
            unsigned ro = (wr * 128u + (q * 2u + a) * 16u + lr) * 128u;
            afr[a][0] = *(const bf16x8*)(As + ro + ((kg     ) ^ x7) * 16u);
            afr[a][1] = *(const bf16x8*)(As + ro + ((kg + 4u) ^ x7) * 16u);
        }
    };
    auto mfmaP = [&](unsigned q, bf16x8 (*afr)[2]) {
        __builtin_amdgcn_s_setprio(1);
        #pragma unroll
        for (int a = 0; a < 2; ++a)
            #pragma unroll
            for (int nf = 0; nf < 4; ++nf) {
                acc[q * 2 + a][nf] = __builtin_amdgcn_mfma_f32_16x16x32_bf16(
                    afr[a][0], bfr[nf][0], acc[q * 2 + a][nf], 0, 0, 0);
                acc[q * 2 + a][nf] = __builtin_amdgcn_mfma_f32_16x16x32_bf16(
                    afr[a][1], bfr[nf][1], acc[q * 2 + a][nf], 0, 0, 0);
            }
        __builtin_amdgcn_s_setprio(0);
    };

    // prologue: B(0), A(0) -> buf0; B(1) -> buf1.  12 gloads/wave in flight.
    stB(0, 0, 0); stB(0, 1, 0);
    stA(0, 0, 0); stA(0, 1, 0);
    stB(1, 0, 1); stB(1, 1, 1);

    for (int t = 0; t < KTg; ++t) {
        unsigned cb = (unsigned)t & 1u;
        // K-tile t fully landed across all waves: own vmcnt then barrier.
        // steady-state outstanding: B(t)4 + A(t)4 + B(t+1)4 = 12 -> keep 4.
        if (t < KTg - 1) asm volatile("s_waitcnt vmcnt(4)" ::: "memory");
        else             asm volatile("s_waitcnt vmcnt(0)" ::: "memory");
        __builtin_amdgcn_s_barrier();

        bf16x8 afr[2][2];
        // ---- phase 0: B all + A m-pair0 reads; stage A-half0(t+1) ----
        loadB(cb);
        loadA(cb, 0, afr);
        if (t + 1 < KTg) stA(cb ^ 1u, 0, t + 1);
        __builtin_amdgcn_sched_barrier(0);
        __builtin_amdgcn_s_barrier();
        asm volatile("s_waitcnt lgkmcnt(0)" ::: "memory");
        mfmaP(0, afr);
        // ---- phase 1: A m-pair1; stage A-half1(t+1) ----
        loadA(cb, 1, afr);
        if (t + 1 < KTg) stA(cb ^ 1u, 1, t + 1);
        __builtin_amdgcn_sched_barrier(0);
        __builtin_amdgcn_s_barrier();
        asm volatile("s_waitcnt lgkmcnt(0)" ::: "memory");
        mfmaP(1, afr);
        // ---- phase 2: A m-pair2; stage B-half0(t+2) into dead B-region ----
        loadA(cb, 2, afr);
        if (t + 2 < KTg) stB(cb, 0, t + 2);
        __builtin_amdgcn_sched_barrier(0);
        __builtin_amdgcn_s_barrier();
        asm volatile("s_waitcnt lgkmcnt(0)" ::: "memory");
        mfmaP(2, afr);
        // ---- phase 3: A m-pair3; stage B-half1(t+2) ----
        loadA(cb, 3, afr);
        if (t + 2 < KTg) stB(cb, 1, t + 2);
        __builtin_amdgcn_sched_barrier(0);
        __builtin_amdgcn_s_barrier();
        asm volatile("s_waitcnt lgkmcnt(0)" ::: "memory");
        mfmaP(3, afr);
    }

    // ---- epilogue: bias + leaky^2 + gelu^2 + exp + row partial sums ----
    // C/D layout: col = lane&15 (=lr), row = kg*4 + j
    unsigned row_base = bm * BMg + wr * 128u;
    unsigned col_base = bn * BNg + wc * 64u;
    float bb[4];
    #pragma unroll
    for (int nf = 0; nf < 4; ++nf) bb[nf] = bias[col_base + nf * 16u + lr];
    #pragma unroll
    for (int mf = 0; mf < 8; ++mf) {
        float s[4] = {0.f, 0.f, 0.f, 0.f};
        #pragma unroll
        for (int nf = 0; nf < 4; ++nf) {
            #pragma unroll
            for (int j = 0; j < 4; ++j) {
                float v = acc[mf][nf][j] + bb[nf];
                v = v > 0.0f ? v : 1e-4f * v;      // two leaky-relus fused
                v = gelu_ss(gelu_ss(v));
                s[j] += __expf(v);
            }
        }
        #pragma unroll
        for (int j = 0; j < 4; ++j) {
            float t = s[j];
            t += __shfl_xor(t, 1);
            t += __shfl_xor(t, 2);
            t += __shfl_xor(t, 4);
            t += __shfl_xor(t, 8);
            if (lr == 0)
                atomicAdd(&rowsum[row_base + mf * 16u + kg * 4u + j], t);
        }
    }
}

// ---------------------------------------------------------------------------
// Fallback (round-2 kernel): fused fp32 staging, used only if ws too small.
// ---------------------------------------------------------------------------
#define BM 256
#define BN 256
#define BK 64
#define NBLK ((MD / BM) * (ND / BN))

__device__ __forceinline__ unsigned swz(unsigned row, unsigned kbyte) {
    return row * (BK * 2u) + (kbyte ^ ((row & 7u) << 4));
}

__global__ __launch_bounds__(512, 1) void fused_gemm_lse(
    const float* __restrict__ x, const float* __restrict__ W,
    const float* __restrict__ bias, float* __restrict__ rowsum)
{
    __shared__ alignas(16) __bf16 lds[2][2][BM * BK];
    unsigned bid  = blockIdx.x;
    unsigned sbid = (bid & 7u) * (NBLK / 8u) + (bid >> 3);
    unsigned bm = sbid / (ND / BN);
    unsigned bn = sbid % (ND / BN);
    const unsigned tid  = threadIdx.x;
    const unsigned lane = tid & 63u;
    const unsigned wid  = tid >> 6;
    const unsigned wr   = wid >> 2;
    const unsigned wc   = wid & 3u;
    const unsigned lr   = lane & 15u;
    const unsigned kg   = lane >> 4;
    const float* gA = x + (size_t)bm * BM * KD;
    const float* gB = W + (size_t)bn * BN * KD;
    const unsigned s_row = tid >> 3;
    const unsigned s_c8  = tid & 7u;
    f32x4 acc[8][4] = {};
    float4 ra[8], rb[8];
    auto issue = [&](const float* g, int kt, float4* r) {
        #pragma unroll
        for (int i = 0; i < 4; ++i) {
            unsigned row = s_row + 64u * i;
            size_t goff = (size_t)row * KD + (size_t)kt * BK + (size_t)s_c8 * 8u;
            r[i * 2]     = *(const float4*)(g + goff);
            r[i * 2 + 1] = *(const float4*)(g + goff + 4);
        }
    };
    auto writeT = [&](char* dst, const float4* r) {
        #pragma unroll
        for (int i = 0; i < 4; ++i) {
            unsigned row = s_row + 64u * i;
            float4 lo = r[i * 2], hi = r[i * 2 + 1];
            bf16x8 v;
            v[0]=(__bf16)lo.x; v[1]=(__bf16)lo.y; v[2]=(__bf16)lo.z; v[3]=(__bf16)lo.w;
            v[4]=(__bf16)hi.x; v[5]=(__bf16)hi.y; v[6]=(__bf16)hi.z; v[7]=(__bf16)hi.w;
            *(bf16x8*)(dst + swz(row, s_c8 * 16u)) = v;
        }
    };
    auto compute = [&](int cur) {
        const char* AsB = (const char*)&lds[cur][0][0];
        const char* BsB = (const char*)&lds[cur][1][0];
        #pragma unroll
        for (int ks = 0; ks < 2; ++ks) {
            unsigned kb = (unsigned)ks * 64u + kg * 16u;
            bf16x8 bfr[4];
            #pragma unroll
            for (int ni = 0; ni < 4; ++ni)
                bfr[ni] = *(const bf16x8*)(BsB + swz(wc * 64u + ni * 16u + lr, kb));
            #pragma unroll
            for (int mh = 0; mh < 2; ++mh) {
                bf16x8 af[4];
                #pragma unroll
                for (int a = 0; a < 4; ++a)
                    af[a] = *(const bf16x8*)(AsB + swz(wr * 128u + mh * 64u + a * 16u + lr, kb));
                __builtin_amdgcn_s_setprio(1);
                #pragma unroll
                for (int a = 0; a < 4; ++a)
                    #pragma unroll
                    for (int ni = 0; ni < 4; ++ni)
                        acc[mh * 4 + a][ni] = __builtin_amdgcn_mfma_f32_16x16x32_bf16(
                            af[a], bfr[ni], acc[mh * 4 + a][ni], 0, 0, 0);
                __builtin_amdgcn_s_setprio(0);
            }
        }
    };
    issue(gA, 0, ra); issue(gB, 0, rb);
    writeT((char*)&lds[0][0][0], ra);
    writeT((char*)&lds[0][1][0], rb);
    __syncthreads();
    int cur = 0;
    for (int kt = 0; kt < KD / BK - 1; ++kt) {
        issue(gA, kt + 1, ra);
        issue(gB, kt + 1, rb);
        compute(cur);
        writeT((char*)&lds[cur ^ 1][0][0], ra);
        writeT((char*)&lds[cur ^ 1][1][0], rb);
        __syncthreads();
        cur ^= 1;
    }
    compute(cur);
    unsigned row_base = bm * BM + wr * 128u;
    unsigned col_base = bn * BN + wc * 64u;
    float bb[4];
    #pragma unroll
    for (int ni = 0; ni < 4; ++ni) bb[ni] = bias[col_base + ni * 16u + lr];
    #pragma unroll
    for (int mi = 0; mi < 8; ++mi) {
        float s[4] = {0.f, 0.f, 0.f, 0.f};
        #pragma unroll
        for (int ni = 0; ni < 4; ++ni) {
            #pragma unroll
            for (int j = 0; j < 4; ++j) {
                float v = acc[mi][ni][j] + bb[ni];
                v = v > 0.0f ? v : 1e-4f * v;
                v = gelu_ss(gelu_ss(v));
                s[j] += __expf(v);
            }
        }
        #pragma unroll
        for (int j = 0; j < 4; ++j) {
            float t = s[j];
            t += __shfl_xor(t, 1);
            t += __shfl_xor(t, 2);
            t += __shfl_xor(t, 4);
            t += __shfl_xor(t, 8);
            if (lr == 0)
                atomicAdd(&rowsum[row_base + mi * 16u + kg * 4u + j], t);
        }
    }
}

__global__ void lse_log(float* __restrict__ out) {
    int i = blockIdx.x * 256 + threadIdx.x;
    if (i < MD) out[i] = logf(out[i]);
}

extern "C" void kernel_launch(void* const* d_in, const int* in_sizes, int n_in,
                              void* d_out, int out_size, void* d_ws, size_t ws_size,
                              hipStream_t stream) {
    (void)in_sizes; (void)n_in; (void)out_size;
    const float* x = (const float*)d_in[0];
    const float* W = (const float*)d_in[1];
    const float* b = (const float*)d_in[2];
    float* out = (float*)d_out;

    hipMemsetAsync(out, 0, (size_t)MD * sizeof(float), stream);

    size_t need = ((size_t)MD * KD + (size_t)ND * KD) * sizeof(__bf16);  // 100.7 MB
    if (ws_size >= need) {
        __bf16* xb = (__bf16*)d_ws;
        __bf16* Wb = xb + (size_t)MD * KD;
        cvt_bf16<<<2048, 256, 0, stream>>>(x, xb, MD * KD / 8);
        cvt_bf16<<<2048, 256, 0, stream>>>(W, Wb, ND * KD / 8);
        gemm_bf16_lse<<<(MD / BMg) * (ND / BNg), 512, 0, stream>>>(xb, Wb, b, out);
    } else {
        fused_gemm_lse<<<NBLK, 512, 0, stream>>>(x, W, b, out);
    }
    lse_log<<<MD / 256, 256, 0, stream>>>(out);
}